// Round 9
// baseline (85.750 us; speedup 1.0000x reference)
//
#include <hip/hip_runtime.h>
#include <math.h>

// Problem constants
#define BB 128
#define ND 32
#define NIJ 16384
#define EPS2 0.25f
#define EPS4 0.0625f

// Tiling: 512 blocks x 32 ij, full batch per block; 256 thr = 128 b x 2 q
#define TIJ 32
#define NBLK (NIJ / TIJ)        // 512 (2-3/CU)
#define NTHR 256
#define ROWF 132                // coef row: cA32|cB32|K32|KV32|pad4

// LDS layout (floats)
#define XS_OFF  4224            // X stage [128][36]
#define CC_OFF  8832
#define LAM_OFF 8864
#define LDS_FL  8896            // 35.6 KB -> 3+ blocks/CU co-resident
#define STG_ROW 36              // epilogue stage aliases coef region [0,4224)

// part layout per block (packed): num[128][32] @0, den[128] @4096
#define PART_STRIDE 4224
#define DEN_OFF_P 4096

__global__ __launch_bounds__(NTHR, 3) void gmm_fused(
    const float* __restrict__ Xg,
    const float* __restrict__ tptr,
    const float* __restrict__ Mu0, const float* __restrict__ Mu1,
    const float* __restrict__ S0,  const float* __restrict__ S1,
    const float* __restrict__ Lam,
    float* __restrict__ part)
{
    __shared__ __align__(16) float lds[LDS_FL];

    const int tid  = threadIdx.x;
    const int blk  = blockIdx.x;
    const int ij0g = blk * TIJ;
    const float t   = tptr[0];
    const float omt = 1.0f - t;

    // ---- Phase 1a: X full batch -> LDS stage [128][36] ----
#pragma unroll
    for (int k = 0; k < (BB * ND) / NTHR; ++k) {
        const int idx = tid + k * NTHR;    // 4096 floats
        lds[XS_OFF + (idx >> 5) * STG_ROW + (idx & 31)] = Xg[idx];
    }

    // ---- Phase 1b: per-(ij, n) coefficients into LDS (each exactly once) ----
    // 32 ij * 32 n = 1024 pairs over 256 threads -> 4 each
#pragma unroll
    for (int k = 0; k < (TIJ * ND) / NTHR; ++k) {
        const int idx = tid + k * NTHR;
        const int ijl = idx >> 5;          // 0..31
        const int n   = idx & 31;
        const int ij  = ij0g + ijl;
        const int i   = ij >> 7;
        const int j   = ij & 127;
        const float s0  = S0[i * ND + n];
        const float s1  = S1[j * ND + n];
        const float mu0 = Mu0[i * ND + n];
        const float mu1 = Mu1[j * ND + n];
        const float Ds  = sqrtf(4.0f * s0 * s1 + EPS4);
        const float Cs  = 0.5f * (Ds - EPS2);
        const float Sigma = omt * omt * s0 + t * t * s1
                          + 2.0f * t * omt * Cs + EPS2 * t * omt;
        const float St  = (t * s1 + omt * Cs) - (omt * s0 + t * Cs) - EPS2 * t;
        const float Mut = omt * mu0 + t * mu1;
        const float v   = mu1 - mu0;
        const float invS = 1.0f / Sigma;
        const float Kf  = St * invS;
        const float cA  = -0.5f * invS;
        const float cB  = Mut * invS;
        lds[ijl * ROWF + n]      = cA;
        lds[ijl * ROWF + 32 + n] = cB;
        lds[ijl * ROWF + 64 + n] = Kf;
        lds[ijl * ROWF + 96 + n] = v - Kf * Mut;
        float cc = cA * Mut * Mut - 0.5f * __logf(Sigma);
        cc += __shfl_xor(cc, 1);
        cc += __shfl_xor(cc, 2);
        cc += __shfl_xor(cc, 4);
        cc += __shfl_xor(cc, 8);
        cc += __shfl_xor(cc, 16);
        if (n == 0) lds[CC_OFF + ijl] = cc;
    }
    if (tid < TIJ) lds[LAM_OFF + tid] = Lam[ij0g + tid];

    __syncthreads();

    // ---- X row for this thread's b -> registers ----
    const int bl = tid >> 1;      // 0..127 b
    const int q  = tid & 1;       // ij-lane
    float x[ND];
#pragma unroll
    for (int c = 0; c < 8; ++c) {
        const float4 v4 = *(const float4*)&lds[XS_OFF + bl * STG_ROW + 4 * c];
        x[4*c+0] = v4.x; x[4*c+1] = v4.y; x[4*c+2] = v4.z; x[4*c+3] = v4.w;
    }

    float num[ND];
#pragma unroll
    for (int n = 0; n < ND; ++n) num[n] = 0.0f;
    float den = 0.0f;

    // ---- Phase 2: thread does 1 b x 16 ij; row reads are 2-addr bcast ----
#pragma unroll
    for (int it = 0; it < TIJ / 2; ++it) {
        const int ijl = q + it * 2;        // 2 distinct rows/wave, bank-disjoint
        const float* __restrict__ row = &lds[ijl * ROWF];
        const float cc0 = lds[CC_OFF + ijl];
        float lwa = cc0, lwb = 0.0f;
#pragma unroll
        for (int nc = 0; nc < 8; ++nc) {
            const float4 a  = *(const float4*)&row[nc * 4];
            const float4 bq = *(const float4*)&row[32 + nc * 4];
            lwa = fmaf(fmaf(a.x, x[nc*4+0], bq.x), x[nc*4+0], lwa);
            lwb = fmaf(fmaf(a.y, x[nc*4+1], bq.y), x[nc*4+1], lwb);
            lwa = fmaf(fmaf(a.z, x[nc*4+2], bq.z), x[nc*4+2], lwa);
            lwb = fmaf(fmaf(a.w, x[nc*4+3], bq.w), x[nc*4+3], lwb);
        }
        float lw = lwa + lwb;
        lw = fminf(fmaxf(lw, -50.0f), 50.0f);
        const float w = __expf(lw) * lds[LAM_OFF + ijl];
        den += w;
#pragma unroll
        for (int nc = 0; nc < 8; ++nc) {
            const float4 kk = *(const float4*)&row[64 + nc * 4];
            const float4 kv = *(const float4*)&row[96 + nc * 4];
            num[nc*4+0] = fmaf(w, fmaf(kk.x, x[nc*4+0], kv.x), num[nc*4+0]);
            num[nc*4+1] = fmaf(w, fmaf(kk.y, x[nc*4+1], kv.y), num[nc*4+1]);
            num[nc*4+2] = fmaf(w, fmaf(kk.z, x[nc*4+2], kv.z), num[nc*4+2]);
            num[nc*4+3] = fmaf(w, fmaf(kk.w, x[nc*4+3], kv.w), num[nc*4+3]);
        }
    }

    // ---- Reduce across the 2 q-lanes (lane bit 0) ----
    den += __shfl_xor(den, 1);
#pragma unroll
    for (int n = 0; n < ND; ++n) num[n] += __shfl_xor(num[n], 1);

    __syncthreads();   // phase-2 LDS reads done before stage overwrites coef

    // ---- Stage into LDS [128][36] rows ----
    if (q == 0) {
#pragma unroll
        for (int c = 0; c < 8; ++c) {
            *(float4*)&lds[bl * STG_ROW + 4 * c] =
                make_float4(num[4*c], num[4*c+1], num[4*c+2], num[4*c+3]);
        }
        lds[bl * STG_ROW + 32] = den;
    }

    __syncthreads();

    // ---- Coalesced packed block store: 4224 floats, full 128B lines ----
    float* __restrict__ dstg = part + (size_t)blk * PART_STRIDE;
#pragma unroll
    for (int k = 0; k < 5; ++k) {
        const int kk = tid + k * NTHR;     // 1056 float4s used
        if (kk < PART_STRIDE / 4) {
            const int p = 4 * kk;
            float4 val;
            if (p < DEN_OFF_P) {
                val = *(const float4*)&lds[(p >> 5) * STG_ROW + (p & 31)];
            } else {
                const int d = p - DEN_OFF_P;
                val = make_float4(lds[(d + 0) * STG_ROW + 32],
                                  lds[(d + 1) * STG_ROW + 32],
                                  lds[(d + 2) * STG_ROW + 32],
                                  lds[(d + 3) * STG_ROW + 32]);
            }
            *(float4*)(dstg + p) = val;
        }
    }
}

// 256 blocks = (b, n-half). Thread (sg, n16): sums 32 slices; LDS combine.
__global__ __launch_bounds__(256) void gmm_reduce(
    const float* __restrict__ part,
    float* __restrict__ out)
{
    const int blk = blockIdx.x;            // 0..255
    const int b   = blk >> 1;
    const int nh  = blk & 1;
    const int tid = threadIdx.x;
    const int n16 = tid & 15;
    const int sg  = tid >> 4;              // 0..15 slice-groups
    const int n   = nh * 16 + n16;

    float num = 0.0f, den = 0.0f;
#pragma unroll
    for (int g = 0; g < 32; ++g) {
        const int s = sg + g * 16;         // slice 0..511
        const size_t base = (size_t)s * PART_STRIDE;
        num += part[base + b * 32 + n];
        den += part[base + DEN_OFF_P + b]; // same addr across n16 -> broadcast
    }

    __shared__ float red[16][18];
    red[sg][n16] = num;
    if (n16 == 0) red[sg][16] = den;
    __syncthreads();

    if (tid < 16) {
        float ns = 0.0f, ds = 0.0f;
#pragma unroll
        for (int k = 0; k < 16; ++k) {
            ns += red[k][tid];
            ds += red[k][16];
        }
        out[b * 32 + nh * 16 + tid] = ns / ds;
    }
}

extern "C" void kernel_launch(void* const* d_in, const int* in_sizes, int n_in,
                              void* d_out, int out_size, void* d_ws, size_t ws_size,
                              hipStream_t stream)
{
    const float* X   = (const float*)d_in[0];
    const float* t   = (const float*)d_in[1];
    const float* Mu0 = (const float*)d_in[2];
    const float* Mu1 = (const float*)d_in[3];
    const float* S0  = (const float*)d_in[4];
    const float* S1  = (const float*)d_in[5];
    const float* Lam = (const float*)d_in[6];
    float* out  = (float*)d_out;
    float* part = (float*)d_ws;             // NBLK * PART_STRIDE floats (8.65 MB)

    gmm_fused<<<NBLK, NTHR, 0, stream>>>(X, t, Mu0, Mu1, S0, S1, Lam, part);
    gmm_reduce<<<2 * BB, 256, 0, stream>>>(part, out);
}